// Round 1
// baseline (690.415 us; speedup 1.0000x reference)
//
#include <hip/hip_runtime.h>

#define S_LEN 2048
#define BATCH 2
#define NH 32
#define NKV 8
#define HD 64
#define HID 2048
#define NTOK (BATCH * S_LEN)   // 4096

typedef __attribute__((ext_vector_type(8))) __bf16 bf16x8;
typedef __attribute__((ext_vector_type(4))) float f32x4;

__device__ inline ushort f2b(float f) {
    union { float f; unsigned u; } x{f};
    unsigned r = (x.u + 0x7fff + ((x.u >> 16) & 1)) >> 16;
    return (ushort)r;
}
__device__ inline float b2f(ushort u) {
    union { unsigned u; float f; } x{(unsigned)u << 16};
    return x.f;
}

// ---------------- fp32 -> bf16 conversion ----------------
__global__ __launch_bounds__(256) void cvt_f32_bf16(const float* __restrict__ in,
                                                    ushort* __restrict__ out, int n4) {
    int i = blockIdx.x * 256 + threadIdx.x;
    if (i >= n4) return;
    float4 v = reinterpret_cast<const float4*>(in)[i];
    ushort4 o;
    o.x = f2b(v.x); o.y = f2b(v.y); o.z = f2b(v.z); o.w = f2b(v.w);
    reinterpret_cast<ushort4*>(out)[i] = o;
}

// ---------------- global -> LDS async helper ----------------
__device__ inline void gl_lds16(const void* g, void* l) {
    __builtin_amdgcn_global_load_lds((const __attribute__((address_space(1))) void*)g,
                                     (__attribute__((address_space(3))) void*)l, 16, 0, 0);
}

// ---------------- GEMM: C[m][n] = sum_k A[m][k] * B[n][k] ----------------
// A: [M][K] bf16 row-major, B: [N][K] bf16 row-major (i.e. hidden @ W.T form).
// 128x128 tile, BK=32, 256 threads (4 waves as 2x2), each wave 64x64.
template<int WF32>
__global__ __launch_bounds__(256) void gemm_bt(const ushort* __restrict__ A,
                                               const ushort* __restrict__ B,
                                               void* __restrict__ C,
                                               int M, int N, int K) {
    __shared__ __align__(16) ushort As[128 * 32];
    __shared__ __align__(16) ushort Bs[128 * 32];
    const int tid = threadIdx.x, lane = tid & 63, w = tid >> 6;
    const int wr = w >> 1, wc = w & 1, l15 = lane & 15, lg = lane >> 4;
    const int m0 = blockIdx.y * 128, n0 = blockIdx.x * 128;

    const ushort* Ag = A + (size_t)(m0 + (tid >> 2)) * K + (tid & 3) * 8;
    const ushort* Bg = B + (size_t)(n0 + (tid >> 2)) * K + (tid & 3) * 8;
    ushort* lA = As + w * 512;
    ushort* lB = Bs + w * 512;

    f32x4 acc[4][4] = {};

    for (int k0 = 0; k0 < K; k0 += 32) {
        __syncthreads();
        gl_lds16(Ag + k0, lA);
        gl_lds16(Ag + (size_t)64 * K + k0, lA + 2048);
        gl_lds16(Bg + k0, lB);
        gl_lds16(Bg + (size_t)64 * K + k0, lB + 2048);
        __syncthreads();   // compiler drains vmcnt before s_barrier

        const ushort* pa = As + (wr * 64 + l15) * 32 + lg * 8;
        const ushort* pb = Bs + (wc * 64 + l15) * 32 + lg * 8;
        bf16x8 af[4], bff[4];
#pragma unroll
        for (int i = 0; i < 4; i++) {
            af[i]  = *(const bf16x8*)(pa + i * 512);
            bff[i] = *(const bf16x8*)(pb + i * 512);
        }
#pragma unroll
        for (int i = 0; i < 4; i++)
#pragma unroll
            for (int j = 0; j < 4; j++)
                acc[i][j] = __builtin_amdgcn_mfma_f32_16x16x32_bf16(af[i], bff[j], acc[i][j], 0, 0, 0);
    }

    const int mr = m0 + wr * 64 + lg * 4, nc = n0 + wc * 64 + l15;
#pragma unroll
    for (int i = 0; i < 4; i++)
#pragma unroll
        for (int j = 0; j < 4; j++)
#pragma unroll
            for (int r = 0; r < 4; r++) {
                size_t row = mr + i * 16 + r, col = nc + j * 16;
                if (WF32) ((float*)C)[row * N + col] = acc[i][j][r];
                else      ((ushort*)C)[row * N + col] = f2b(acc[i][j][r]);
            }
}

// ---------------- RoPE (in place, bf16) ----------------
// X: [NTOK][nheads*64]; pair (d, d+32) within each head.
__global__ __launch_bounds__(256) void rope_k(ushort* __restrict__ X, int nheads, int total) {
    int idx = blockIdx.x * 256 + threadIdx.x;
    int np = nheads * 32;
    if (idx >= total) return;
    int t = idx / np, p = idx - t * np;
    int hh = p >> 5, i = p & 31;
    int pos = t & (S_LEN - 1);
    // inv_freq = 10000^(-2i/64) = 2^(-i * log2(10000)/32)
    float ang = (float)pos * exp2f(-(float)i * 0.4152410118609203f);
    float sv, cv;
    sincosf(ang, &sv, &cv);
    ushort* base = X + (size_t)t * (nheads * 64) + hh * 64 + i;
    float x1 = b2f(base[0]), x2 = b2f(base[32]);
    base[0]  = f2b(x1 * cv - x2 * sv);
    base[32] = f2b(x2 * cv + x1 * sv);
}

// ---------------- V transpose: [b][s][kvh*64+d] -> Vt[b][kvh][d][s] ----------------
__global__ __launch_bounds__(256) void transpose_v(const ushort* __restrict__ V,
                                                   ushort* __restrict__ Vt) {
    __shared__ ushort tile[32][33];
    int bz = blockIdx.z, b = bz >> 3, kvh = bz & 7;
    int s0 = blockIdx.x * 32, d0 = blockIdx.y * 32;
    int tx = threadIdx.x & 31, ty = threadIdx.x >> 5;   // ty: 0..7
#pragma unroll
    for (int i = 0; i < 4; i++)
        tile[ty + i * 8][tx] = V[(size_t)(b * S_LEN + s0 + ty + i * 8) * (NKV * HD) + kvh * 64 + d0 + tx];
    __syncthreads();
#pragma unroll
    for (int i = 0; i < 4; i++)
        Vt[((size_t)((b * 8 + kvh) * 64 + d0 + ty + i * 8)) * S_LEN + s0 + tx] = tile[tx][ty + i * 8];
}

// ---------------- Flash attention (causal, GQA) ----------------
// Q: [NTOK][2048] bf16 (roped), K: [NTOK][512] bf16 (roped), Vt: [B][KVH][64][S] bf16
// O: [NTOK][2048] bf16. grid (S/64, B*H); 4 waves/block, 16 q-rows/wave, KV tiles of 32.
__global__ __launch_bounds__(256) void attn_k(const ushort* __restrict__ Q,
                                              const ushort* __restrict__ Kc,
                                              const ushort* __restrict__ Vt,
                                              ushort* __restrict__ O) {
    __shared__ __align__(16) ushort P_lds[4][16 * 40];   // per-wave, padded stride 40
    const int lane = threadIdx.x & 63, w = threadIdx.x >> 6;
    const int l15 = lane & 15, lg = lane >> 4;
    const int bh = blockIdx.y, b = bh >> 5, h = bh & 31, kvh = h >> 2;
    const int q0 = blockIdx.x * 64 + w * 16;

    const ushort* qb = Q + (size_t)(b * S_LEN + q0 + l15) * HID + h * 64 + lg * 8;
    bf16x8 qf0 = *(const bf16x8*)qb;
    bf16x8 qf1 = *(const bf16x8*)(qb + 32);

    f32x4 ao[4] = {};
    float mrow[4] = {-INFINITY, -INFINITY, -INFINITY, -INFINITY};
    float lrow[4] = {0.f, 0.f, 0.f, 0.f};

    const ushort* Kb = Kc + (size_t)(b * S_LEN) * (NKV * HD) + kvh * 64 + lg * 8;
    const ushort* Vb = Vt + ((size_t)((b * 8 + kvh) * 64 + l15)) * S_LEN + lg * 8;
    ushort* pl = &P_lds[w][0];

    const int ktend = (q0 + 15) >> 5;
    for (int kt = 0; kt <= ktend; ++kt) {
        const int kn = kt * 32;
        const ushort* k0p = Kb + (size_t)(kn + l15) * (NKV * HD);
        const ushort* k1p = k0p + 16 * (NKV * HD);
        bf16x8 kf00 = *(const bf16x8*)k0p,        kf01 = *(const bf16x8*)(k0p + 32);
        bf16x8 kf10 = *(const bf16x8*)k1p,        kf11 = *(const bf16x8*)(k1p + 32);

        f32x4 s0 = {}, s1 = {};
        s0 = __builtin_amdgcn_mfma_f32_16x16x32_bf16(qf0, kf00, s0, 0, 0, 0);
        s0 = __builtin_amdgcn_mfma_f32_16x16x32_bf16(qf1, kf01, s0, 0, 0, 0);
        s1 = __builtin_amdgcn_mfma_f32_16x16x32_bf16(qf0, kf10, s1, 0, 0, 0);
        s1 = __builtin_amdgcn_mfma_f32_16x16x32_bf16(qf1, kf11, s1, 0, 0, 0);

        float pm[4];
#pragma unroll
        for (int r = 0; r < 4; r++) {
            int row = q0 + lg * 4 + r;
            float a = (kn + l15      <= row) ? s0[r] * 0.125f : -INFINITY;
            float c = (kn + 16 + l15 <= row) ? s1[r] * 0.125f : -INFINITY;
            s0[r] = a; s1[r] = c;
            pm[r] = fmaxf(a, c);
        }
#pragma unroll
        for (int off = 1; off < 16; off <<= 1)
#pragma unroll
            for (int r = 0; r < 4; r++) pm[r] = fmaxf(pm[r], __shfl_xor(pm[r], off, 64));

        float sc[4], rs[4];
#pragma unroll
        for (int r = 0; r < 4; r++) {
            float mn = fmaxf(mrow[r], pm[r]);
            sc[r] = expf(mrow[r] - mn);        // first tile: exp(-inf) = 0
            mrow[r] = mn;
            s0[r] = expf(s0[r] - mn);          // masked: exp(-inf) = 0
            s1[r] = expf(s1[r] - mn);
            rs[r] = s0[r] + s1[r];
        }
#pragma unroll
        for (int off = 1; off < 16; off <<= 1)
#pragma unroll
            for (int r = 0; r < 4; r++) rs[r] += __shfl_xor(rs[r], off, 64);
#pragma unroll
        for (int r = 0; r < 4; r++) lrow[r] = lrow[r] * sc[r] + rs[r];
#pragma unroll
        for (int dt = 0; dt < 4; dt++)
#pragma unroll
            for (int r = 0; r < 4; r++) ao[dt][r] *= sc[r];

        // P (C-layout) -> LDS -> A-fragment layout
#pragma unroll
        for (int r = 0; r < 4; r++) {
            pl[(lg * 4 + r) * 40 + l15]      = f2b(s0[r]);
            pl[(lg * 4 + r) * 40 + 16 + l15] = f2b(s1[r]);
        }
        bf16x8 pf = *(const bf16x8*)(pl + l15 * 40 + lg * 8);

#pragma unroll
        for (int dt = 0; dt < 4; dt++) {
            bf16x8 vf = *(const bf16x8*)(Vb + (size_t)dt * 16 * S_LEN + kn);
            ao[dt] = __builtin_amdgcn_mfma_f32_16x16x32_bf16(pf, vf, ao[dt], 0, 0, 0);
        }
    }

    float inv[4];
#pragma unroll
    for (int r = 0; r < 4; r++) inv[r] = 1.0f / lrow[r];
    ushort* ob = O + (size_t)(b * S_LEN + q0 + lg * 4) * HID + h * 64 + l15;
#pragma unroll
    for (int dt = 0; dt < 4; dt++)
#pragma unroll
        for (int r = 0; r < 4; r++)
            ob[(size_t)r * HID + dt * 16] = f2b(ao[dt][r] * inv[r]);
}

// ---------------- launch ----------------
extern "C" void kernel_launch(void* const* d_in, const int* in_sizes, int n_in,
                              void* d_out, int out_size, void* d_ws, size_t ws_size,
                              hipStream_t stream) {
    const float* hidden = (const float*)d_in[0];
    const float* Wq = (const float*)d_in[1];
    const float* Wk = (const float*)d_in[2];
    const float* Wv = (const float*)d_in[3];
    const float* Wo = (const float*)d_in[4];

    char* ws = (char*)d_ws;
    size_t off = 0;
    auto alloc = [&](size_t bytes) -> void* {
        void* p = ws + off;
        off += (bytes + 255) & ~(size_t)255;
        return p;
    };
    ushort* hb  = (ushort*)alloc((size_t)NTOK * HID * 2);
    ushort* wq  = (ushort*)alloc((size_t)2048 * 2048 * 2);
    ushort* wk  = (ushort*)alloc((size_t)512 * 2048 * 2);
    ushort* wv  = (ushort*)alloc((size_t)512 * 2048 * 2);
    ushort* wo  = (ushort*)alloc((size_t)2048 * 2048 * 2);
    ushort* Qb  = (ushort*)alloc((size_t)NTOK * 2048 * 2);
    ushort* Kb  = (ushort*)alloc((size_t)NTOK * 512 * 2);
    ushort* Vb  = (ushort*)alloc((size_t)NTOK * 512 * 2);
    ushort* Vtb = (ushort*)alloc((size_t)NTOK * 512 * 2);
    ushort* AO  = (ushort*)alloc((size_t)NTOK * 2048 * 2);

    auto cvt = [&](const float* in, ushort* out, int n) {
        int n4 = n / 4;
        cvt_f32_bf16<<<(n4 + 255) / 256, 256, 0, stream>>>(in, out, n4);
    };
    cvt(hidden, hb, NTOK * HID);
    cvt(Wq, wq, 2048 * 2048);
    cvt(Wk, wk, 512 * 2048);
    cvt(Wv, wv, 512 * 2048);
    cvt(Wo, wo, 2048 * 2048);

    gemm_bt<0><<<dim3(16, 32), 256, 0, stream>>>(hb, wq, Qb, NTOK, 2048, 2048);
    gemm_bt<0><<<dim3(4, 32), 256, 0, stream>>>(hb, wk, Kb, NTOK, 512, 2048);
    gemm_bt<0><<<dim3(4, 32), 256, 0, stream>>>(hb, wv, Vb, NTOK, 512, 2048);

    rope_k<<<(NTOK * NH * 32 + 255) / 256, 256, 0, stream>>>(Qb, NH, NTOK * NH * 32);
    rope_k<<<(NTOK * NKV * 32 + 255) / 256, 256, 0, stream>>>(Kb, NKV, NTOK * NKV * 32);
    transpose_v<<<dim3(S_LEN / 32, 2, BATCH * NKV), 256, 0, stream>>>(Vb, Vtb);

    attn_k<<<dim3(S_LEN / 64, BATCH * NH), 256, 0, stream>>>(Qb, Kb, Vtb, AO);

    gemm_bt<1><<<dim3(16, 32), 256, 0, stream>>>(AO, wo, d_out, NTOK, 2048, 2048);
}

// Round 2
// 688.089 us; speedup vs baseline: 1.0034x; 1.0034x over previous
//
#include <hip/hip_runtime.h>

#define S_LEN 2048
#define BATCH 2
#define NH 32
#define NKV 8
#define HD 64
#define HID 2048
#define NTOK (BATCH * S_LEN)   // 4096

typedef __attribute__((ext_vector_type(8))) __bf16 bf16x8;
typedef __attribute__((ext_vector_type(4))) float f32x4;

__device__ inline ushort f2b(float f) {
    union { float f; unsigned u; } x{f};
    unsigned r = (x.u + 0x7fff + ((x.u >> 16) & 1)) >> 16;
    return (ushort)r;
}
__device__ inline float b2f(ushort u) {
    union { unsigned u; float f; } x{(unsigned)u << 16};
    return x.f;
}
__device__ inline ushort f2b_fast(float f) {
    __bf16 h = (__bf16)f;
    union { __bf16 h; ushort u; } x{h};
    return x.u;
}

// ---------------- fp32 -> bf16 conversion ----------------
__global__ __launch_bounds__(256) void cvt_f32_bf16(const float* __restrict__ in,
                                                    ushort* __restrict__ out, int n4) {
    int i = blockIdx.x * 256 + threadIdx.x;
    if (i >= n4) return;
    float4 v = reinterpret_cast<const float4*>(in)[i];
    ushort4 o;
    o.x = f2b(v.x); o.y = f2b(v.y); o.z = f2b(v.z); o.w = f2b(v.w);
    reinterpret_cast<ushort4*>(out)[i] = o;
}

// ---------------- global -> LDS async helper ----------------
__device__ inline void gl_lds16(const void* g, void* l) {
    __builtin_amdgcn_global_load_lds((const __attribute__((address_space(1))) void*)g,
                                     (__attribute__((address_space(3))) void*)l, 16, 0, 0);
}

// ---------------- GEMM: C[m][n] = sum_k A[m][k] * B[n][k] ----------------
template<int WF32>
__global__ __launch_bounds__(256) void gemm_bt(const ushort* __restrict__ A,
                                               const ushort* __restrict__ B,
                                               void* __restrict__ C,
                                               int M, int N, int K) {
    __shared__ __align__(16) ushort As[128 * 32];
    __shared__ __align__(16) ushort Bs[128 * 32];
    const int tid = threadIdx.x, lane = tid & 63, w = tid >> 6;
    const int wr = w >> 1, wc = w & 1, l15 = lane & 15, lg = lane >> 4;
    const int m0 = blockIdx.y * 128, n0 = blockIdx.x * 128;

    const ushort* Ag = A + (size_t)(m0 + (tid >> 2)) * K + (tid & 3) * 8;
    const ushort* Bg = B + (size_t)(n0 + (tid >> 2)) * K + (tid & 3) * 8;
    ushort* lA = As + w * 512;
    ushort* lB = Bs + w * 512;

    f32x4 acc[4][4] = {};

    for (int k0 = 0; k0 < K; k0 += 32) {
        __syncthreads();
        gl_lds16(Ag + k0, lA);
        gl_lds16(Ag + (size_t)64 * K + k0, lA + 2048);
        gl_lds16(Bg + k0, lB);
        gl_lds16(Bg + (size_t)64 * K + k0, lB + 2048);
        __syncthreads();

        const ushort* pa = As + (wr * 64 + l15) * 32 + lg * 8;
        const ushort* pb = Bs + (wc * 64 + l15) * 32 + lg * 8;
        bf16x8 af[4], bff[4];
#pragma unroll
        for (int i = 0; i < 4; i++) {
            af[i]  = *(const bf16x8*)(pa + i * 512);
            bff[i] = *(const bf16x8*)(pb + i * 512);
        }
#pragma unroll
        for (int i = 0; i < 4; i++)
#pragma unroll
            for (int j = 0; j < 4; j++)
                acc[i][j] = __builtin_amdgcn_mfma_f32_16x16x32_bf16(af[i], bff[j], acc[i][j], 0, 0, 0);
    }

    const int mr = m0 + wr * 64 + lg * 4, nc = n0 + wc * 64 + l15;
#pragma unroll
    for (int i = 0; i < 4; i++)
#pragma unroll
        for (int j = 0; j < 4; j++)
#pragma unroll
            for (int r = 0; r < 4; r++) {
                size_t row = mr + i * 16 + r, col = nc + j * 16;
                if (WF32) ((float*)C)[row * N + col] = acc[i][j][r];
                else      ((ushort*)C)[row * N + col] = f2b(acc[i][j][r]);
            }
}

// ---------------- RoPE (in place, bf16) ----------------
__global__ __launch_bounds__(256) void rope_k(ushort* __restrict__ X, int nheads, int total) {
    int idx = blockIdx.x * 256 + threadIdx.x;
    int np = nheads * 32;
    if (idx >= total) return;
    int t = idx / np, p = idx - t * np;
    int hh = p >> 5, i = p & 31;
    int pos = t & (S_LEN - 1);
    float ang = (float)pos * exp2f(-(float)i * 0.4152410118609203f);
    float sv, cv;
    sincosf(ang, &sv, &cv);
    ushort* base = X + (size_t)t * (nheads * 64) + hh * 64 + i;
    float x1 = b2f(base[0]), x2 = b2f(base[32]);
    base[0]  = f2b(x1 * cv - x2 * sv);
    base[32] = f2b(x2 * cv + x1 * sv);
}

// ---------------- V transpose ----------------
__global__ __launch_bounds__(256) void transpose_v(const ushort* __restrict__ V,
                                                   ushort* __restrict__ Vt) {
    __shared__ ushort tile[32][33];
    int bz = blockIdx.z, b = bz >> 3, kvh = bz & 7;
    int s0 = blockIdx.x * 32, d0 = blockIdx.y * 32;
    int tx = threadIdx.x & 31, ty = threadIdx.x >> 5;
#pragma unroll
    for (int i = 0; i < 4; i++)
        tile[ty + i * 8][tx] = V[(size_t)(b * S_LEN + s0 + ty + i * 8) * (NKV * HD) + kvh * 64 + d0 + tx];
    __syncthreads();
#pragma unroll
    for (int i = 0; i < 4; i++)
        Vt[((size_t)((b * 8 + kvh) * 64 + d0 + ty + i * 8)) * S_LEN + s0 + tx] = tile[tx][ty + i * 8];
}

// ---------------- Flash attention (causal, GQA) ----------------
// KVBLK=64, prefetch K(t+1)/V(t), exp2 softmax, diagonal-only masking,
// exact defer-max. 4 waves/block, 16 q-rows/wave.
#define C_SCL 0.18033688011112042f   // 0.125 * log2(e)

__global__ __launch_bounds__(256) void attn_k(const ushort* __restrict__ Q,
                                              const ushort* __restrict__ Kc,
                                              const ushort* __restrict__ Vt,
                                              ushort* __restrict__ O) {
    __shared__ __align__(16) ushort P_lds[4][16 * 72];   // row stride 72 (16B-aligned)
    const int lane = threadIdx.x & 63, w = threadIdx.x >> 6;
    const int l15 = lane & 15, lg = lane >> 4;
    const int bh = blockIdx.y, b = bh >> 5, h = bh & 31, kvh = h >> 2;
    const int q0 = blockIdx.x * 64 + w * 16;
    const int KROW = NKV * HD;   // 512

    const ushort* qb = Q + (size_t)(b * S_LEN + q0 + l15) * HID + h * 64 + lg * 8;
    bf16x8 qf0 = *(const bf16x8*)qb;
    bf16x8 qf1 = *(const bf16x8*)(qb + 32);

    f32x4 ao[4] = {};
    float mrow[4] = {-INFINITY, -INFINITY, -INFINITY, -INFINITY};
    float lrow[4] = {0.f, 0.f, 0.f, 0.f};

    const ushort* Kb = Kc + (size_t)(b * S_LEN) * KROW + kvh * 64 + lg * 8;
    const ushort* Vb = Vt + ((size_t)((b * 8 + kvh) * 64 + l15)) * S_LEN + lg * 8;
    ushort* pl = &P_lds[w][0];

    const int ktend = (q0 + 15) >> 6;

    bf16x8 kf[4][2];
#pragma unroll
    for (int kc = 0; kc < 4; kc++) {
        const ushort* kp = Kb + (size_t)(kc * 16 + l15) * KROW;
        kf[kc][0] = *(const bf16x8*)kp;
        kf[kc][1] = *(const bf16x8*)(kp + 32);
    }

    for (int kt = 0; kt <= ktend; ++kt) {
        const int kn = kt << 6;

        // ---- QK^T (16 x 64 scores) ----
        f32x4 s[4];
#pragma unroll
        for (int kc = 0; kc < 4; kc++) {
            f32x4 z = {};
            z = __builtin_amdgcn_mfma_f32_16x16x32_bf16(qf0, kf[kc][0], z, 0, 0, 0);
            z = __builtin_amdgcn_mfma_f32_16x16x32_bf16(qf1, kf[kc][1], z, 0, 0, 0);
            s[kc] = z;
        }

        // ---- issue V loads for this tile (consumed after softmax) ----
        bf16x8 vf[4][2];
#pragma unroll
        for (int dt = 0; dt < 4; dt++)
#pragma unroll
            for (int c2 = 0; c2 < 2; c2++)
                vf[dt][c2] = *(const bf16x8*)(Vb + (size_t)dt * 16 * S_LEN + kn + c2 * 32);

        // ---- prefetch K for next tile ----
        if (kt < ktend) {
            const int kn2 = kn + 64;
#pragma unroll
            for (int kc = 0; kc < 4; kc++) {
                const ushort* kp = Kb + (size_t)(kn2 + kc * 16 + l15) * KROW;
                kf[kc][0] = *(const bf16x8*)kp;
                kf[kc][1] = *(const bf16x8*)(kp + 32);
            }
        }

        // ---- causal mask (diagonal tile only) ----
        if (kt == ktend) {
#pragma unroll
            for (int kc = 0; kc < 4; kc++)
#pragma unroll
                for (int r = 0; r < 4; r++) {
                    int row = q0 + lg * 4 + r;
                    s[kc][r] = (kn + kc * 16 + l15 <= row) ? s[kc][r] : -INFINITY;
                }
        }

        // ---- row max (within regs, then across 16-lane group) ----
        float pm[4];
#pragma unroll
        for (int r = 0; r < 4; r++)
            pm[r] = fmaxf(fmaxf(s[0][r], s[1][r]), fmaxf(s[2][r], s[3][r]));
#pragma unroll
        for (int off = 1; off < 16; off <<= 1)
#pragma unroll
            for (int r = 0; r < 4; r++) pm[r] = fmaxf(pm[r], __shfl_xor(pm[r], off, 64));

        // ---- exact defer-max: rescale only when the max grew ----
        float g = fmaxf(fmaxf(pm[0] - mrow[0], pm[1] - mrow[1]),
                        fmaxf(pm[2] - mrow[2], pm[3] - mrow[3]));
        if (!__all(g <= 0.f)) {
            float sc[4];
#pragma unroll
            for (int r = 0; r < 4; r++) {
                float mn = fmaxf(mrow[r], pm[r]);
                sc[r] = exp2f((mrow[r] - mn) * C_SCL);  // first tile: exp2(-inf)=0
                mrow[r] = mn;
                lrow[r] *= sc[r];
            }
#pragma unroll
            for (int dt = 0; dt < 4; dt++)
#pragma unroll
                for (int r = 0; r < 4; r++) ao[dt][r] *= sc[r];
        }

        // ---- exp2((s - m) * c), row sum, P -> LDS ----
        float neg[4], rs[4];
#pragma unroll
        for (int r = 0; r < 4; r++) neg[r] = -mrow[r] * C_SCL;
#pragma unroll
        for (int kc = 0; kc < 4; kc++)
#pragma unroll
            for (int r = 0; r < 4; r++)
                s[kc][r] = exp2f(fmaf(s[kc][r], C_SCL, neg[r]));
#pragma unroll
        for (int r = 0; r < 4; r++)
            rs[r] = (s[0][r] + s[1][r]) + (s[2][r] + s[3][r]);
#pragma unroll
        for (int off = 1; off < 16; off <<= 1)
#pragma unroll
            for (int r = 0; r < 4; r++) rs[r] += __shfl_xor(rs[r], off, 64);
#pragma unroll
        for (int r = 0; r < 4; r++) lrow[r] += rs[r];

#pragma unroll
        for (int kc = 0; kc < 4; kc++)
#pragma unroll
            for (int r = 0; r < 4; r++)
                pl[(lg * 4 + r) * 72 + kc * 16 + l15] = f2b_fast(s[kc][r]);

        bf16x8 pf0 = *(const bf16x8*)(pl + l15 * 72 + lg * 8);
        bf16x8 pf1 = *(const bf16x8*)(pl + l15 * 72 + 32 + lg * 8);

        // ---- PV ----
#pragma unroll
        for (int dt = 0; dt < 4; dt++) {
            ao[dt] = __builtin_amdgcn_mfma_f32_16x16x32_bf16(pf0, vf[dt][0], ao[dt], 0, 0, 0);
            ao[dt] = __builtin_amdgcn_mfma_f32_16x16x32_bf16(pf1, vf[dt][1], ao[dt], 0, 0, 0);
        }
    }

    float inv[4];
#pragma unroll
    for (int r = 0; r < 4; r++) inv[r] = 1.0f / lrow[r];
    ushort* ob = O + (size_t)(b * S_LEN + q0 + lg * 4) * HID + h * 64 + l15;
#pragma unroll
    for (int dt = 0; dt < 4; dt++)
#pragma unroll
        for (int r = 0; r < 4; r++)
            ob[(size_t)r * HID + dt * 16] = f2b(ao[dt][r] * inv[r]);
}

// ---------------- launch ----------------
extern "C" void kernel_launch(void* const* d_in, const int* in_sizes, int n_in,
                              void* d_out, int out_size, void* d_ws, size_t ws_size,
                              hipStream_t stream) {
    const float* hidden = (const float*)d_in[0];
    const float* Wq = (const float*)d_in[1];
    const float* Wk = (const float*)d_in[2];
    const float* Wv = (const float*)d_in[3];
    const float* Wo = (const float*)d_in[4];

    char* ws = (char*)d_ws;
    size_t off = 0;
    auto alloc = [&](size_t bytes) -> void* {
        void* p = ws + off;
        off += (bytes + 255) & ~(size_t)255;
        return p;
    };
    ushort* hb  = (ushort*)alloc((size_t)NTOK * HID * 2);
    ushort* wq  = (ushort*)alloc((size_t)2048 * 2048 * 2);
    ushort* wk  = (ushort*)alloc((size_t)512 * 2048 * 2);
    ushort* wv  = (ushort*)alloc((size_t)512 * 2048 * 2);
    ushort* wo  = (ushort*)alloc((size_t)2048 * 2048 * 2);
    ushort* Qb  = (ushort*)alloc((size_t)NTOK * 2048 * 2);
    ushort* Kb  = (ushort*)alloc((size_t)NTOK * 512 * 2);
    ushort* Vb  = (ushort*)alloc((size_t)NTOK * 512 * 2);
    ushort* Vtb = (ushort*)alloc((size_t)NTOK * 512 * 2);
    ushort* AO  = (ushort*)alloc((size_t)NTOK * 2048 * 2);

    auto cvt = [&](const float* in, ushort* out, int n) {
        int n4 = n / 4;
        cvt_f32_bf16<<<(n4 + 255) / 256, 256, 0, stream>>>(in, out, n4);
    };
    cvt(hidden, hb, NTOK * HID);
    cvt(Wq, wq, 2048 * 2048);
    cvt(Wk, wk, 512 * 2048);
    cvt(Wv, wv, 512 * 2048);
    cvt(Wo, wo, 2048 * 2048);

    gemm_bt<0><<<dim3(16, 32), 256, 0, stream>>>(hb, wq, Qb, NTOK, 2048, 2048);
    gemm_bt<0><<<dim3(4, 32), 256, 0, stream>>>(hb, wk, Kb, NTOK, 512, 2048);
    gemm_bt<0><<<dim3(4, 32), 256, 0, stream>>>(hb, wv, Vb, NTOK, 512, 2048);

    rope_k<<<(NTOK * NH * 32 + 255) / 256, 256, 0, stream>>>(Qb, NH, NTOK * NH * 32);
    rope_k<<<(NTOK * NKV * 32 + 255) / 256, 256, 0, stream>>>(Kb, NKV, NTOK * NKV * 32);
    transpose_v<<<dim3(S_LEN / 32, 2, BATCH * NKV), 256, 0, stream>>>(Vb, Vtb);

    attn_k<<<dim3(S_LEN / 64, BATCH * NH), 256, 0, stream>>>(Qb, Kb, Vtb, AO);

    gemm_bt<1><<<dim3(16, 32), 256, 0, stream>>>(AO, wo, d_out, NTOK, 2048, 2048);
}

// Round 3
// 427.636 us; speedup vs baseline: 1.6145x; 1.6091x over previous
//
#include <hip/hip_runtime.h>

#define S_LEN 2048
#define BATCH 2
#define NH 32
#define NKV 8
#define HD 64
#define HID 2048
#define NTOK (BATCH * S_LEN)   // 4096

typedef __attribute__((ext_vector_type(8))) __bf16 bf16x8;
typedef __attribute__((ext_vector_type(4))) float f32x4;

__device__ inline ushort f2b(float f) {
    union { float f; unsigned u; } x{f};
    unsigned r = (x.u + 0x7fff + ((x.u >> 16) & 1)) >> 16;
    return (ushort)r;
}
__device__ inline float b2f(ushort u) {
    union { unsigned u; float f; } x{(unsigned)u << 16};
    return x.f;
}

// ---------------- fp32 -> bf16 conversion ----------------
__global__ __launch_bounds__(256) void cvt_f32_bf16(const float* __restrict__ in,
                                                    ushort* __restrict__ out, int n4) {
    int i = blockIdx.x * 256 + threadIdx.x;
    if (i >= n4) return;
    float4 v = reinterpret_cast<const float4*>(in)[i];
    ushort4 o;
    o.x = f2b(v.x); o.y = f2b(v.y); o.z = f2b(v.z); o.w = f2b(v.w);
    reinterpret_cast<ushort4*>(out)[i] = o;
}

// ---------------- global -> LDS async helper ----------------
__device__ inline void gl_lds16(const void* g, void* l) {
    __builtin_amdgcn_global_load_lds((const __attribute__((address_space(1))) void*)g,
                                     (__attribute__((address_space(3))) void*)l, 16, 0, 0);
}

// ---------------- GEMM: C[m][n] = sum_k A[m][k] * B[n][k] ----------------
template<int WF32>
__global__ __launch_bounds__(256) void gemm_bt(const ushort* __restrict__ A,
                                               const ushort* __restrict__ B,
                                               void* __restrict__ C,
                                               int M, int N, int K) {
    __shared__ __align__(16) ushort As[128 * 32];
    __shared__ __align__(16) ushort Bs[128 * 32];
    const int tid = threadIdx.x, lane = tid & 63, w = tid >> 6;
    const int wr = w >> 1, wc = w & 1, l15 = lane & 15, lg = lane >> 4;
    const int m0 = blockIdx.y * 128, n0 = blockIdx.x * 128;

    const ushort* Ag = A + (size_t)(m0 + (tid >> 2)) * K + (tid & 3) * 8;
    const ushort* Bg = B + (size_t)(n0 + (tid >> 2)) * K + (tid & 3) * 8;
    ushort* lA = As + w * 512;
    ushort* lB = Bs + w * 512;

    f32x4 acc[4][4] = {};

    for (int k0 = 0; k0 < K; k0 += 32) {
        __syncthreads();
        gl_lds16(Ag + k0, lA);
        gl_lds16(Ag + (size_t)64 * K + k0, lA + 2048);
        gl_lds16(Bg + k0, lB);
        gl_lds16(Bg + (size_t)64 * K + k0, lB + 2048);
        __syncthreads();

        const ushort* pa = As + (wr * 64 + l15) * 32 + lg * 8;
        const ushort* pb = Bs + (wc * 64 + l15) * 32 + lg * 8;
        bf16x8 af[4], bff[4];
#pragma unroll
        for (int i = 0; i < 4; i++) {
            af[i]  = *(const bf16x8*)(pa + i * 512);
            bff[i] = *(const bf16x8*)(pb + i * 512);
        }
#pragma unroll
        for (int i = 0; i < 4; i++)
#pragma unroll
            for (int j = 0; j < 4; j++)
                acc[i][j] = __builtin_amdgcn_mfma_f32_16x16x32_bf16(af[i], bff[j], acc[i][j], 0, 0, 0);
    }

    const int mr = m0 + wr * 64 + lg * 4, nc = n0 + wc * 64 + l15;
#pragma unroll
    for (int i = 0; i < 4; i++)
#pragma unroll
        for (int j = 0; j < 4; j++)
#pragma unroll
            for (int r = 0; r < 4; r++) {
                size_t row = mr + i * 16 + r, col = nc + j * 16;
                if (WF32) ((float*)C)[row * N + col] = acc[i][j][r];
                else      ((ushort*)C)[row * N + col] = f2b(acc[i][j][r]);
            }
}

// ---------------- RoPE (in place, bf16) ----------------
__global__ __launch_bounds__(256) void rope_k(ushort* __restrict__ X, int nheads, int stride, int total) {
    int idx = blockIdx.x * 256 + threadIdx.x;
    int np = nheads * 32;
    if (idx >= total) return;
    int t = idx / np, p = idx - t * np;
    int hh = p >> 5, i = p & 31;
    int pos = t & (S_LEN - 1);
    float ang = (float)pos * exp2f(-(float)i * 0.4152410118609203f);
    float sv, cv;
    sincosf(ang, &sv, &cv);
    ushort* base = X + (size_t)t * stride + hh * 64 + i;
    float x1 = b2f(base[0]), x2 = b2f(base[32]);
    base[0]  = f2b(x1 * cv - x2 * sv);
    base[32] = f2b(x2 * cv + x1 * sv);
}

// ---------------- V transpose: from KV buffer (stride 1024, V at +512) ----------------
__global__ __launch_bounds__(256) void transpose_v(const ushort* __restrict__ KV,
                                                   ushort* __restrict__ Vt) {
    __shared__ ushort tile[32][33];
    int bz = blockIdx.z, b = bz >> 3, kvh = bz & 7;
    int s0 = blockIdx.x * 32, d0 = blockIdx.y * 32;
    int tx = threadIdx.x & 31, ty = threadIdx.x >> 5;
#pragma unroll
    for (int i = 0; i < 4; i++)
        tile[ty + i * 8][tx] = KV[(size_t)(b * S_LEN + s0 + ty + i * 8) * 1024 + 512 + kvh * 64 + d0 + tx];
    __syncthreads();
#pragma unroll
    for (int i = 0; i < 4; i++)
        Vt[((size_t)((b * 8 + kvh) * 64 + d0 + ty + i * 8)) * S_LEN + s0 + tx] = tile[tx][ty + i * 8];
}

// ---------------- Flash attention (causal, GQA) ----------------
// Swapped QK^T (lane owns one q row), permuted K rows so P is born in
// PV A-fragment order (no LDS, no shuffles for P). Paired q-tiles for
// uniform block work. K/V prefetched one tile ahead.
#define C_SCL 0.18033688011112042f   // 0.125 * log2(e)

__global__ __launch_bounds__(256) void attn_k(const ushort* __restrict__ Q,
                                              const ushort* __restrict__ Kc,   // KV buffer, stride 1024
                                              const ushort* __restrict__ Vt,
                                              ushort* __restrict__ O) {
    const int lane = threadIdx.x & 63, w = threadIdx.x >> 6;
    const int l15 = lane & 15, lg = lane >> 4;
    const int bh = blockIdx.y, b = bh >> 5, h = bh & 31, kvh = h >> 2;
    const int KROW = 1024;

    const ushort* KbaseH = Kc + (size_t)(b * S_LEN) * KROW + kvh * 64 + lg * 8;
    const ushort* Vb = Vt + ((size_t)((b * 8 + kvh) * 64 + l15)) * S_LEN + lg * 8;

    // permuted kv-row offset for QK^T MFMA kc at A-fragment row l15:
    // chosen so output reg (kc,r) at lane-group lg holds kv = 32*(kc>>1)+8*lg+4*(kc&1)+r
    int kvoff[4];
#pragma unroll
    for (int kc = 0; kc < 4; kc++)
        kvoff[kc] = ((kc >> 1) << 5) + ((l15 >> 2) << 3) + ((kc & 1) << 2) + (l15 & 3);

    for (int half = 0; half < 2; ++half) {
        const int bx = half ? (31 - blockIdx.x) : blockIdx.x;
        const int q0 = bx * 64 + w * 16;
        const int qrow = q0 + l15;
        const int ktend = bx;

        const ushort* qb = Q + (size_t)(b * S_LEN + qrow) * HID + h * 64 + lg * 8;
        bf16x8 qf0 = *(const bf16x8*)qb;
        bf16x8 qf1 = *(const bf16x8*)(qb + 32);

        f32x4 ao[4] = {};
        float m = -INFINITY, l = 0.f;

        bf16x8 kf[4][2], vf[4][2];
        auto load_k = [&](int kn) {
#pragma unroll
            for (int kc = 0; kc < 4; kc++) {
                const ushort* kp = KbaseH + (size_t)(kn + kvoff[kc]) * KROW;
                kf[kc][0] = *(const bf16x8*)kp;
                kf[kc][1] = *(const bf16x8*)(kp + 32);
            }
        };
        auto load_v = [&](int kn) {
#pragma unroll
            for (int dt = 0; dt < 4; dt++) {
                const ushort* vp = Vb + (size_t)dt * 16 * S_LEN + kn;
                vf[dt][0] = *(const bf16x8*)vp;
                vf[dt][1] = *(const bf16x8*)(vp + 32);
            }
        };
        load_k(0);
        load_v(0);

        for (int kt = 0; kt <= ktend; ++kt) {
            const int kn = kt << 6;

            // ---- QK^T (swapped: A=K, B=Q) -> s[kc][r] = S[q=l15][kv] ----
            f32x4 s[4];
#pragma unroll
            for (int kc = 0; kc < 4; kc++) {
                f32x4 z = {};
                z = __builtin_amdgcn_mfma_f32_16x16x32_bf16(kf[kc][0], qf0, z, 0, 0, 0);
                z = __builtin_amdgcn_mfma_f32_16x16x32_bf16(kf[kc][1], qf1, z, 0, 0, 0);
                s[kc] = z;
            }
            if (kt < ktend) load_k(kn + 64);   // prefetch next K (overlaps softmax+PV)

            // ---- causal mask (diagonal tile only) ----
            if (kt == ktend) {
#pragma unroll
                for (int kc = 0; kc < 4; kc++)
#pragma unroll
                    for (int r = 0; r < 4; r++) {
                        int kv = kn + ((kc >> 1) << 5) + (lg << 3) + ((kc & 1) << 2) + r;
                        s[kc][r] = (kv <= qrow) ? s[kc][r] : -INFINITY;
                    }
            }

            // ---- row max: 15 in-reg + 2 shfl rounds ----
            float pm = s[0][0];
#pragma unroll
            for (int kc = 0; kc < 4; kc++)
#pragma unroll
                for (int r = 0; r < 4; r++) pm = fmaxf(pm, s[kc][r]);
            pm = fmaxf(pm, __shfl_xor(pm, 16, 64));
            pm = fmaxf(pm, __shfl_xor(pm, 32, 64));

            // ---- exact defer-max rescale ----
            if (!__all(pm <= m)) {
                float mn = fmaxf(m, pm);
                float sc = exp2f((m - mn) * C_SCL);   // first tile: 0
                m = mn;
                l *= sc;
                float scr[4];
#pragma unroll
                for (int r = 0; r < 4; r++) scr[r] = __shfl(sc, (lg << 2) + r, 64);
#pragma unroll
                for (int dt = 0; dt < 4; dt++)
#pragma unroll
                    for (int r = 0; r < 4; r++) ao[dt][r] *= scr[r];
            }

            // ---- exp2, in-lane partial sum, pack P in A-fragment order ----
            const float nb = -m * C_SCL;
            float ps = 0.f;
            bf16x8 pf0, pf1;
#pragma unroll
            for (int r = 0; r < 4; r++) {
                float p0 = exp2f(fmaf(s[0][r], C_SCL, nb));
                float p1 = exp2f(fmaf(s[1][r], C_SCL, nb));
                float p2 = exp2f(fmaf(s[2][r], C_SCL, nb));
                float p3 = exp2f(fmaf(s[3][r], C_SCL, nb));
                ps += (p0 + p1) + (p2 + p3);
                pf0[r]     = (__bf16)p0;
                pf0[4 + r] = (__bf16)p1;
                pf1[r]     = (__bf16)p2;
                pf1[4 + r] = (__bf16)p3;
            }
            l += ps;

            // ---- PV ----
#pragma unroll
            for (int dt = 0; dt < 4; dt++) {
                ao[dt] = __builtin_amdgcn_mfma_f32_16x16x32_bf16(pf0, vf[dt][0], ao[dt], 0, 0, 0);
                ao[dt] = __builtin_amdgcn_mfma_f32_16x16x32_bf16(pf1, vf[dt][1], ao[dt], 0, 0, 0);
            }
            if (kt < ktend) load_v(kn + 64);   // prefetch next V (overlaps next QK^T+softmax)
        }

        // ---- epilogue: one l-reduction, normalize, store ----
        l += __shfl_xor(l, 16, 64);
        l += __shfl_xor(l, 32, 64);
        float inv = 1.0f / l;
        float invr[4];
#pragma unroll
        for (int r = 0; r < 4; r++) invr[r] = __shfl(inv, (lg << 2) + r, 64);
        ushort* ob = O + (size_t)(b * S_LEN + q0 + lg * 4) * HID + h * 64 + l15;
#pragma unroll
        for (int dt = 0; dt < 4; dt++)
#pragma unroll
            for (int r = 0; r < 4; r++)
                ob[(size_t)r * HID + dt * 16] = f2b(ao[dt][r] * invr[r]);
    }
}

// ---------------- launch ----------------
extern "C" void kernel_launch(void* const* d_in, const int* in_sizes, int n_in,
                              void* d_out, int out_size, void* d_ws, size_t ws_size,
                              hipStream_t stream) {
    const float* hidden = (const float*)d_in[0];
    const float* Wq = (const float*)d_in[1];
    const float* Wk = (const float*)d_in[2];
    const float* Wv = (const float*)d_in[3];
    const float* Wo = (const float*)d_in[4];

    char* ws = (char*)d_ws;
    size_t off = 0;
    auto alloc = [&](size_t bytes) -> void* {
        void* p = ws + off;
        off += (bytes + 255) & ~(size_t)255;
        return p;
    };
    ushort* hb  = (ushort*)alloc((size_t)NTOK * HID * 2);
    ushort* wq  = (ushort*)alloc((size_t)2048 * 2048 * 2);
    ushort* wkv = (ushort*)alloc((size_t)1024 * 2048 * 2);
    ushort* wo  = (ushort*)alloc((size_t)2048 * 2048 * 2);
    ushort* Qb  = (ushort*)alloc((size_t)NTOK * 2048 * 2);
    ushort* KVb = (ushort*)alloc((size_t)NTOK * 1024 * 2);
    ushort* Vtb = (ushort*)alloc((size_t)NTOK * 512 * 2);
    ushort* AO  = (ushort*)alloc((size_t)NTOK * 2048 * 2);

    auto cvt = [&](const float* in, ushort* out, int n) {
        int n4 = n / 4;
        cvt_f32_bf16<<<(n4 + 255) / 256, 256, 0, stream>>>(in, out, n4);
    };
    cvt(hidden, hb, NTOK * HID);
    cvt(Wq, wq, 2048 * 2048);
    cvt(Wk, wkv, 512 * 2048);
    cvt(Wv, wkv + (size_t)512 * 2048, 512 * 2048);
    cvt(Wo, wo, 2048 * 2048);

    gemm_bt<0><<<dim3(16, 32), 256, 0, stream>>>(hb, wq, Qb, NTOK, 2048, 2048);
    gemm_bt<0><<<dim3(8, 32), 256, 0, stream>>>(hb, wkv, KVb, NTOK, 1024, 2048);

    rope_k<<<(NTOK * NH * 32 + 255) / 256, 256, 0, stream>>>(Qb, NH, 2048, NTOK * NH * 32);
    rope_k<<<(NTOK * NKV * 32 + 255) / 256, 256, 0, stream>>>(KVb, NKV, 1024, NTOK * NKV * 32);
    transpose_v<<<dim3(S_LEN / 32, 2, BATCH * NKV), 256, 0, stream>>>(KVb, Vtb);

    attn_k<<<dim3(16, BATCH * NH), 256, 0, stream>>>(Qb, KVb, Vtb, AO);

    gemm_bt<1><<<dim3(16, 32), 256, 0, stream>>>(AO, wo, d_out, NTOK, 2048, 2048);
}